// Round 14
// baseline (100.571 us; speedup 1.0000x reference)
//
#include <hip/hip_runtime.h>
#include <hip/hip_bf16.h>
#include <hip/hip_fp16.h>
#include <stdint.h>

// ---------------------------------------------------------------------------
// GroundingLoss fused pipeline, R14.
// R11==R13 (~98us): sim_fp8 is VALU-epilogue-bound (~400 cyc softmax/tile vs
// ~68 cyc matrix/tile) with NO phase overlap (short K-loop -> all waves hit
// epilogue in lockstep). R14: (a) wave loops 4 b-pairs (phase stagger across
// waves/blocks; MFMA drain overlaps next loads), (b) epilogue4 processes the
// 4 tiles phase-interleaved (4 indep exp/fma chains, batched shuffles),
// (c) red_kernel fused into loss_fused (reads Sp directly) -> 3 launches.
// A-pair staged once to 16KB LDS (R13-verified indices). Fixed harness cost
// (256MB ws poison ~44us + restore ~3us) is untouchable.
// ---------------------------------------------------------------------------

typedef __attribute__((ext_vector_type(8))) short short8;    // 8 bf16 = 16B
typedef __attribute__((ext_vector_type(16))) float float16;  // 32x32 acc
typedef __attribute__((ext_vector_type(8))) int int8v;       // fp8 K=64 frag
typedef __attribute__((ext_vector_type(4))) int int4v;       // 16B

typedef const __attribute__((address_space(1))) unsigned int* gptr_as1;
typedef __attribute__((address_space(3))) unsigned int* lptr_as3;

#define NTOK 256
#define KDIM 256

__device__ __forceinline__ unsigned short f2bf(float f) {
    unsigned int u = __float_as_uint(f);
    unsigned int r = (u + 0x7fffu + ((u >> 16) & 1u)) >> 16;  // RNE
    return (unsigned short)r;
}

__device__ __forceinline__ short8 cvt8(const float* p) {
    float4 f0 = ((const float4*)p)[0];
    float4 f1 = ((const float4*)p)[1];
    short8 v;
    v[0] = (short)f2bf(f0.x); v[1] = (short)f2bf(f0.y);
    v[2] = (short)f2bf(f0.z); v[3] = (short)f2bf(f0.w);
    v[4] = (short)f2bf(f1.x); v[5] = (short)f2bf(f1.y);
    v[6] = (short)f2bf(f1.z); v[7] = (short)f2bf(f1.w);
    return v;
}

// ======================= fp8 path =======================
// q layout (int4v 16B units): [0..65535] x-lo, [65536..] x-hi,
// [131072..] z-lo, [196608..] z-hi. Unit idx = (g*4 + ks)*64 + lane;
// lane: row = lane&31, k0 = ks*64 + (lane>>5)*32; lo = k0..+15, hi = +16..31.
__global__ void conv_fp8(const float* __restrict__ x,
                         const float* __restrict__ z,
                         int4v* __restrict__ q,
                         float* __restrict__ out0) {
    const int uid = blockIdx.x * 256 + threadIdx.x;   // < 131072
    if (uid == 0) out0[0] = 0.0f;                     // loss accumulator
    const int tensor = uid >> 16;                     // 0 = x, 1 = z
    const int idx    = uid & 65535;
    const int g    = idx >> 8;
    const int r    = idx & 255;
    const int ks   = r >> 6;
    const int lane = r & 63;
    const int row  = g * 32 + (lane & 31);
    const int k0   = ks * 64 + (lane >> 5) * 32;
    const float4* p = (const float4*)((tensor ? z : x) + row * KDIM + k0);

    int4v lo, hi;
#pragma unroll
    for (int i = 0; i < 4; i++) {
        float4 f = p[i];
        int v = __builtin_amdgcn_cvt_pk_fp8_f32(f.x, f.y, 0, false);
        v = __builtin_amdgcn_cvt_pk_fp8_f32(f.z, f.w, v, true);
        lo[i] = v;
    }
#pragma unroll
    for (int i = 0; i < 4; i++) {
        float4 f = p[4 + i];
        int v = __builtin_amdgcn_cvt_pk_fp8_f32(f.x, f.y, 0, false);
        v = __builtin_amdgcn_cvt_pk_fp8_f32(f.z, f.w, v, true);
        hi[i] = v;
    }
    q[tensor * 131072 + idx]         = lo;
    q[tensor * 131072 + 65536 + idx] = hi;
}

__device__ __forceinline__ int8v mk8(int4v lo, int4v hi) {
    int8v r;
    r[0] = lo[0]; r[1] = lo[1]; r[2] = lo[2]; r[3] = lo[3];
    r[4] = hi[0]; r[5] = hi[1]; r[6] = hi[2]; r[7] = hi[3];
    return r;
}

#define MFMA_FP8(a, b, c) \
    __builtin_amdgcn_mfma_scale_f32_32x32x64_f8f6f4((a), (b), (c), 0, 0, 0, 0x7F7F7F7F, 0, 0x7F7F7F7F)

__device__ __forceinline__ float tile_max(const float16& c) {
    float m8[8], m4[4];
#pragma unroll
    for (int r = 0; r < 8; r++) m8[r] = fmaxf(c[2 * r], c[2 * r + 1]);
#pragma unroll
    for (int r = 0; r < 4; r++) m4[r] = fmaxf(m8[2 * r], m8[2 * r + 1]);
    return fmaxf(fmaxf(m4[0], m4[1]), fmaxf(m4[2], m4[3]));
}

// Phase-interleaved epilogue of 4 tiles (2a x 2b). Per-lane store of column
// value to Sp[a,b,lane] (halves duplicated; loss_fused divides by 64).
__device__ __forceinline__ void epilogue4(const float16& c0, const float16& c1,
                                          const float16& c2, const float16& c3,
                                          __half* __restrict__ Sp,
                                          int ag0, int bg, int lane) {
    // phase 1: per-tile max trees + batched cross-half shuffles
    float m0 = tile_max(c0), m1 = tile_max(c1), m2 = tile_max(c2), m3 = tile_max(c3);
    m0 = fmaxf(m0, __shfl_xor(m0, 32, 64));
    m1 = fmaxf(m1, __shfl_xor(m1, 32, 64));
    m2 = fmaxf(m2, __shfl_xor(m2, 32, 64));
    m3 = fmaxf(m3, __shfl_xor(m3, 32, 64));

    // phase 2: 4 independent exp/accumulate chains, element-interleaved
    float s0 = 0.f, s1 = 0.f, s2 = 0.f, s3 = 0.f;
    float w0 = 0.f, w1 = 0.f, w2 = 0.f, w3 = 0.f;
#pragma unroll
    for (int r = 0; r < 16; r++) {
        float e0 = __expf(c0[r] - m0); s0 += e0; w0 = fmaf(e0, c0[r], w0);
        float e1 = __expf(c1[r] - m1); s1 += e1; w1 = fmaf(e1, c1[r], w1);
        float e2 = __expf(c2[r] - m2); s2 += e2; w2 = fmaf(e2, c2[r], w2);
        float e3 = __expf(c3[r] - m3); s3 += e3; w3 = fmaf(e3, c3[r], w3);
    }

    // phase 3: batched cross-half sums, rcp, store
    s0 += __shfl_xor(s0, 32, 64); w0 += __shfl_xor(w0, 32, 64);
    s1 += __shfl_xor(s1, 32, 64); w1 += __shfl_xor(w1, 32, 64);
    s2 += __shfl_xor(s2, 32, 64); w2 += __shfl_xor(w2, 32, 64);
    s3 += __shfl_xor(s3, 32, 64); w3 += __shfl_xor(w3, 32, 64);
    float v0 = w0 * __builtin_amdgcn_rcpf(s0);
    float v1 = w1 * __builtin_amdgcn_rcpf(s1);
    float v2 = w2 * __builtin_amdgcn_rcpf(s2);
    float v3 = w3 * __builtin_amdgcn_rcpf(s3);
    Sp[((((ag0 + 0) << 8) + bg + 0) << 6) + lane] = __float2half_rn(v0);
    Sp[((((ag0 + 0) << 8) + bg + 1) << 6) + lane] = __float2half_rn(v1);
    Sp[((((ag0 + 1) << 8) + bg + 0) << 6) + lane] = __float2half_rn(v2);
    Sp[((((ag0 + 1) << 8) + bg + 1) << 6) + lane] = __float2half_rn(v3);
}

// grid = 1024 (128 a-pairs x 8 b-ranges), 256 threads, 3 waves/SIMD.
// Block: a-pair (2 groups, full K) in 16KB LDS. Wave w: b-groups
// brange*32 + w*8 .. +7, as 4 pairs -> phases stagger across waves/blocks.
__global__ __launch_bounds__(256, 3)
void sim_fp8(const int4v* __restrict__ q, __half* __restrict__ Sp) {
    __shared__ int4v sA[1024];   // 16 KB: chunk c = ai*8 + ks*2 + h, 64 units each

    const int tid  = threadIdx.x;
    const int lane = tid & 63;
    const int w    = tid >> 6;

    const int apair  = blockIdx.x >> 3;       // 0..127
    const int brange = blockIdx.x & 7;        // 0..7
    const int ag0    = apair * 2;
    const int bbase  = brange * 32 + w * 8;

    // stage A: 16 chunks of 64 units; wave w stages chunks {w, 4+w, 8+w, 12+w}
#pragma unroll
    for (int i = 0; i < 4; i++) {
        const int c  = i * 4 + w;             // wave-uniform, 0..15
        const int ai = c >> 3;
        const int ks = (c >> 1) & 3;
        const int h  = c & 1;
        const int4v* g = q + h * 65536 + ((ag0 + ai) * 4 + ks) * 64 + lane;
        int4v* l = &sA[c * 64];
        __builtin_amdgcn_global_load_lds((gptr_as1)g, (lptr_as3)l, 16, 0, 0);
    }
    __syncthreads();

    const int4v* zq = q + 131072;

#pragma unroll 1
    for (int p = 0; p < 4; p++) {
        const int bg = bbase + 2 * p;

        float16 acc00, acc01, acc10, acc11;
#pragma unroll
        for (int r = 0; r < 16; r++) { acc00[r] = 0.f; acc01[r] = 0.f; acc10[r] = 0.f; acc11[r] = 0.f; }

#pragma unroll
        for (int ks = 0; ks < 4; ks++) {
            const int u0 = ((bg + 0) * 4 + ks) * 64 + lane;
            const int u1 = ((bg + 1) * 4 + ks) * 64 + lane;
            int8v Ba = mk8(zq[u0], zq[65536 + u0]);
            int8v Bb = mk8(zq[u1], zq[65536 + u1]);
            const int a0 = (ks * 2) * 64 + lane;       // ai=0: chunks ks*2, ks*2+1
            const int a1 = (8 + ks * 2) * 64 + lane;   // ai=1: chunks 8+ks*2, +1
            int8v A0 = mk8(sA[a0], sA[a0 + 64]);
            int8v A1 = mk8(sA[a1], sA[a1 + 64]);
            acc00 = MFMA_FP8(A0, Ba, acc00);
            acc01 = MFMA_FP8(A0, Bb, acc01);
            acc10 = MFMA_FP8(A1, Ba, acc10);
            acc11 = MFMA_FP8(A1, Bb, acc11);
        }

        epilogue4(acc00, acc01, acc10, acc11, Sp, ag0, bg, lane);
    }
}

// Fused Sp->per-n loss: 256 blocks (block n) x 256 threads (thread k).
// rowS[k] = mean of tile (n,k); colS[k] = mean of tile (k,n). Then lse over
// k for both directions, diag = rowS[n]; one atomicAdd per block.
__global__ void loss_fused(const __half* __restrict__ Sp, float* __restrict__ out) {
    const int n    = blockIdx.x;
    const int k    = threadIdx.x;
    const int lane = k & 63;
    const int wv   = k >> 6;

    const __half2* rp = (const __half2*)(Sp + ((size_t)(n * 256 + k) << 6));
    const __half2* cp = (const __half2*)(Sp + ((size_t)(k * 256 + n) << 6));
    float rs = 0.f, cs = 0.f;
#pragma unroll
    for (int i = 0; i < 32; i++) {
        float2 f = __half22float2(rp[i]);
        rs += f.x + f.y;
    }
#pragma unroll
    for (int i = 0; i < 32; i++) {
        float2 f = __half22float2(cp[i]);
        cs += f.x + f.y;
    }
    rs *= (1.0f / 64.0f);
    cs *= (1.0f / 64.0f);

    __shared__ float shm[8];
    __shared__ float shs[8];
    __shared__ float sdiag;
    if (k == n) sdiag = rs;

    // max reduce both dirs
    float mr = rs, mc = cs;
#pragma unroll
    for (int off = 1; off < 64; off <<= 1) {
        mr = fmaxf(mr, __shfl_xor(mr, off, 64));
        mc = fmaxf(mc, __shfl_xor(mc, off, 64));
    }
    if (lane == 0) { shm[wv] = mr; shm[4 + wv] = mc; }
    __syncthreads();
    mr = fmaxf(fmaxf(shm[0], shm[1]), fmaxf(shm[2], shm[3]));
    mc = fmaxf(fmaxf(shm[4], shm[5]), fmaxf(shm[6], shm[7]));

    // sum of exp both dirs
    float er = __expf(rs - mr), ec = __expf(cs - mc);
#pragma unroll
    for (int off = 1; off < 64; off <<= 1) {
        er += __shfl_xor(er, off, 64);
        ec += __shfl_xor(ec, off, 64);
    }
    if (lane == 0) { shs[wv] = er; shs[4 + wv] = ec; }
    __syncthreads();
    if (k == 0) {
        float sr = (shs[0] + shs[1]) + (shs[2] + shs[3]);
        float sc = (shs[4] + shs[5]) + (shs[6] + shs[7]);
        float lse_row = mr + __logf(sr);
        float lse_col = mc + __logf(sc);
        atomicAdd(out, (lse_row + lse_col - 2.0f * sdiag) * (1.0f / 256.0f));
    }
}

// ======================= bf16 fallback (R10-proven) =======================
__global__ void conv_kernel(const float* __restrict__ x,
                            const float* __restrict__ z,
                            short8* __restrict__ outbf,
                            float* __restrict__ out0) {
    const int uid = blockIdx.x * 256 + threadIdx.x;
    if (uid == 0) out0[0] = 0.0f;
    const int u = uid & 262143;
    const float* src = (uid < 262144) ? x : z;
    const int g  = u >> 10;
    const int r  = u & 1023;
    const int ks = r >> 6;
    const int h  = (r >> 5) & 1;
    const int l  = r & 31;
    outbf[uid] = cvt8(src + ((g * 32 + l) * KDIM + ks * 16 + h * 8));
}

__device__ __forceinline__ void tile_epilogue_bf(const float16& c, float* __restrict__ S,
                                                 int a, int b, int lane) {
    float m = tile_max(c);
    m = fmaxf(m, __shfl_xor(m, 32, 64));

    float s0 = 0.f, s1 = 0.f, s2 = 0.f, s3 = 0.f;
    float w0 = 0.f, w1 = 0.f, w2 = 0.f, w3 = 0.f;
#pragma unroll
    for (int r = 0; r < 16; r += 4) {
        float e0 = __expf(c[r + 0] - m);
        float e1 = __expf(c[r + 1] - m);
        float e2 = __expf(c[r + 2] - m);
        float e3 = __expf(c[r + 3] - m);
        s0 += e0; s1 += e1; s2 += e2; s3 += e3;
        w0 = fmaf(e0, c[r + 0], w0);
        w1 = fmaf(e1, c[r + 1], w1);
        w2 = fmaf(e2, c[r + 2], w2);
        w3 = fmaf(e3, c[r + 3], w3);
    }
    float se  = (s0 + s1) + (s2 + s3);
    float swe = (w0 + w1) + (w2 + w3);
    se  += __shfl_xor(se, 32, 64);
    swe += __shfl_xor(swe, 32, 64);
    float cv = swe * __builtin_amdgcn_rcpf(se);
#pragma unroll
    for (int off = 1; off < 32; off <<= 1) cv += __shfl_xor(cv, off, 64);
    if (lane == 0) S[a * NTOK + b] = cv * (1.0f / 32.0f);
}

#define MFMA_BF16 __builtin_amdgcn_mfma_f32_32x32x16_bf16

template <bool F32SRC>
__global__ __launch_bounds__(256, 2)
void sim_kernel(const short8* __restrict__ xbf, const short8* __restrict__ zbf,
                const float* __restrict__ xf, const float* __restrict__ zf,
                float* __restrict__ S) {
    __shared__ short8 sA[4096];

    const int tid  = threadIdx.x;
    const int lane = tid & 63;
    const int w    = tid >> 6;
    const int l31  = lane & 31;
    const int half = lane >> 5;

    const int ablk = blockIdx.x >> 5;
    const int bblk = blockIdx.x & 31;
    const int ag0  = ablk * 4;
    const int bg0  = bblk * 8 + w * 2;

    float16 acc[4][2];
#pragma unroll
    for (int ai = 0; ai < 4; ai++)
#pragma unroll
        for (int bi = 0; bi < 2; bi++)
#pragma unroll
            for (int r = 0; r < 16; r++) acc[ai][bi][r] = 0.0f;

    if (!F32SRC) {
        const short8* asrc = xbf + (size_t)ablk * 4096;
#pragma unroll
        for (int i = 0; i < 16; i++) {
            const short8* g = asrc + i * 256 + w * 64 + lane;
            short8* l = &sA[i * 256 + w * 64];
            __builtin_amdgcn_global_load_lds((gptr_as1)g, (lptr_as3)l, 16, 0, 0);
        }
        __syncthreads();

        const short8* pb0 = zbf + (bg0 + 0) * 1024 + lane;
        const short8* pb1 = zbf + (bg0 + 1) * 1024 + lane;
        short8 Ba = pb0[0];
        short8 Bb = pb1[0];
#pragma unroll
        for (int ks = 0; ks < 16; ks++) {
            short8 Na, Nb;
            if (ks < 15) { Na = pb0[(ks + 1) * 64]; Nb = pb1[(ks + 1) * 64]; }
            short8 A0 = sA[ks * 64 + lane];
            short8 A1 = sA[1024 + ks * 64 + lane];
            short8 A2 = sA[2048 + ks * 64 + lane];
            short8 A3 = sA[3072 + ks * 64 + lane];
            acc[0][0] = MFMA_BF16(A0, Ba, acc[0][0], 0, 0, 0);
            acc[0][1] = MFMA_BF16(A0, Bb, acc[0][1], 0, 0, 0);
            acc[1][0] = MFMA_BF16(A1, Ba, acc[1][0], 0, 0, 0);
            acc[1][1] = MFMA_BF16(A1, Bb, acc[1][1], 0, 0, 0);
            acc[2][0] = MFMA_BF16(A2, Ba, acc[2][0], 0, 0, 0);
            acc[2][1] = MFMA_BF16(A2, Bb, acc[2][1], 0, 0, 0);
            acc[3][0] = MFMA_BF16(A3, Ba, acc[3][0], 0, 0, 0);
            acc[3][1] = MFMA_BF16(A3, Bb, acc[3][1], 0, 0, 0);
            Ba = Na; Bb = Nb;
        }
    } else {
        const float* fb0 = zf + (((bg0 + 0) * 32 + l31) * KDIM + half * 8);
        const float* fb1 = zf + (((bg0 + 1) * 32 + l31) * KDIM + half * 8);
#pragma unroll 1
        for (int ks = 0; ks < 16; ks++) {
            short8 Ba = cvt8(fb0 + ks * 16);
            short8 Bb = cvt8(fb1 + ks * 16);
#pragma unroll
            for (int ai = 0; ai < 4; ai++) {
                const float* fa = xf + (((ag0 + ai) * 32 + l31) * KDIM + half * 8);
                short8 Af = cvt8(fa + ks * 16);
                acc[ai][0] = MFMA_BF16(Af, Ba, acc[ai][0], 0, 0, 0);
                acc[ai][1] = MFMA_BF16(Af, Bb, acc[ai][1], 0, 0, 0);
            }
        }
    }

#pragma unroll
    for (int ai = 0; ai < 4; ai++)
#pragma unroll
        for (int bi = 0; bi < 2; bi++)
            tile_epilogue_bf(acc[ai][bi], S, ag0 + ai, bg0 + bi, lane);
}

__global__ void loss_part(const float* __restrict__ S, float* __restrict__ out) {
    const int lane = threadIdx.x & 63;
    const int wid  = threadIdx.x >> 6;
    const int n    = blockIdx.x * 4 + wid;

    float cv[4], rv[4];
#pragma unroll
    for (int k = 0; k < 4; k++) {
        const int t = lane + 64 * k;
        cv[k] = S[t * NTOK + n];
        rv[k] = S[n * NTOK + t];
    }
    float m = fmaxf(fmaxf(cv[0], cv[1]), fmaxf(cv[2], cv[3]));
#pragma unroll
    for (int off = 1; off < 64; off <<= 1) m = fmaxf(m, __shfl_xor(m, off, 64));
    float s = 0.0f;
#pragma unroll
    for (int k = 0; k < 4; k++) s += __expf(cv[k] - m);
#pragma unroll
    for (int off = 1; off < 64; off <<= 1) s += __shfl_xor(s, off, 64);
    float lse_col = m + __logf(s);

    float m2 = fmaxf(fmaxf(rv[0], rv[1]), fmaxf(rv[2], rv[3]));
#pragma unroll
    for (int off = 1; off < 64; off <<= 1) m2 = fmaxf(m2, __shfl_xor(m2, off, 64));
    float s2 = 0.0f;
#pragma unroll
    for (int k = 0; k < 4; k++) s2 += __expf(rv[k] - m2);
#pragma unroll
    for (int off = 1; off < 64; off <<= 1) s2 += __shfl_xor(s2, off, 64);
    float lse_row = m2 + __logf(s2);

    __shared__ float red[4];
    if (lane == 0) {
        float diag = S[n * NTOK + n];
        red[wid] = (lse_col - diag) + (lse_row - diag);
    }
    __syncthreads();
    if (threadIdx.x == 0)
        atomicAdd(out, (red[0] + red[1] + red[2] + red[3]) * (1.0f / 256.0f));
}

__global__ void zero_kernel(float* __restrict__ out) {
    out[0] = 0.0f;
}

extern "C" void kernel_launch(void* const* d_in, const int* in_sizes, int n_in,
                              void* d_out, int out_size, void* d_ws, size_t ws_size,
                              hipStream_t stream) {
    const float* x = (const float*)d_in[0];   // [256,32,256]
    const float* z = (const float*)d_in[1];   // [256,32,256]
    float* out = (float*)d_out;

    const size_t q_bytes  = 262144ull * 16ull;           // 4 MB fp8 (lo/hi planes)
    const size_t sp_bytes = 65536ull * 64ull * 2ull;     // 8 MB fp16 Sp
    const size_t s_bytes  = 256ull * 256ull * 4ull;      // 256 KB
    const size_t bf_bytes = 524288ull * 16ull;           // 8 MB bf16 (fallback)

    if (ws_size >= q_bytes + sp_bytes) {
        int4v*  q  = (int4v*)d_ws;
        __half* Sp = (__half*)((char*)d_ws + q_bytes);
        conv_fp8<<<512, 256, 0, stream>>>(x, z, q, out);
        sim_fp8<<<1024, 256, 0, stream>>>(q, Sp);
        loss_fused<<<256, 256, 0, stream>>>(Sp, out);
    } else if (ws_size >= bf_bytes + s_bytes) {
        short8* xbf = (short8*)d_ws;
        short8* zbf = xbf + 262144;
        float*  S   = (float*)((char*)d_ws + bf_bytes);
        conv_kernel<<<2048, 256, 0, stream>>>(x, z, (short8*)d_ws, out);
        sim_kernel<false><<<2048, 256, 0, stream>>>(xbf, zbf, nullptr, nullptr, S);
        loss_part<<<64, 256, 0, stream>>>(S, out);
    } else {
        float* S = (float*)d_ws;
        zero_kernel<<<1, 1, 0, stream>>>(out);
        sim_kernel<true><<<2048, 256, 0, stream>>>(nullptr, nullptr, x, z, S);
        loss_part<<<64, 256, 0, stream>>>(S, out);
    }
}

// Round 15
// 96.334 us; speedup vs baseline: 1.0440x; 1.0440x over previous
//
#include <hip/hip_runtime.h>
#include <hip/hip_bf16.h>
#include <hip/hip_fp16.h>
#include <stdint.h>

// ---------------------------------------------------------------------------
// GroundingLoss fused pipeline, R15 (consolidation).
// Session law: every sim variant = ~4x its MFMA floor (MfmaUtil ~25%) across
// 6 structures; best total = R11 (97.2us). R15 = R11's sim_fp8 verbatim with
// ONE change: compact Sp (store lanes 0..31 only -> 4MB, halves Sp write+read
// traffic) + red/loss fused into loss_fused (4 -> 3 graph nodes). This is a
// single-variable test of node overhead + Sp traffic; if neutral, the
// controllable floor is sim's unexplained 4x and we're at the practical
// roofline (fixed harness cost: 256MB ws poison ~44.5us + restore ~3us).
// ---------------------------------------------------------------------------

typedef __attribute__((ext_vector_type(8))) short short8;    // 8 bf16 = 16B
typedef __attribute__((ext_vector_type(16))) float float16;  // 32x32 acc
typedef __attribute__((ext_vector_type(8))) int int8v;       // fp8 K=64 frag
typedef __attribute__((ext_vector_type(4))) int int4v;       // 16B

typedef const __attribute__((address_space(1))) unsigned int* gptr_as1;
typedef __attribute__((address_space(3))) unsigned int* lptr_as3;

#define NTOK 256
#define KDIM 256

__device__ __forceinline__ unsigned short f2bf(float f) {
    unsigned int u = __float_as_uint(f);
    unsigned int r = (u + 0x7fffu + ((u >> 16) & 1u)) >> 16;  // RNE
    return (unsigned short)r;
}

__device__ __forceinline__ short8 cvt8(const float* p) {
    float4 f0 = ((const float4*)p)[0];
    float4 f1 = ((const float4*)p)[1];
    short8 v;
    v[0] = (short)f2bf(f0.x); v[1] = (short)f2bf(f0.y);
    v[2] = (short)f2bf(f0.z); v[3] = (short)f2bf(f0.w);
    v[4] = (short)f2bf(f1.x); v[5] = (short)f2bf(f1.y);
    v[6] = (short)f2bf(f1.z); v[7] = (short)f2bf(f1.w);
    return v;
}

// ======================= fp8 path =======================
// q layout (int4v 16B units): [0..65535] x-lo, [65536..] x-hi,
// [131072..] z-lo, [196608..] z-hi. Unit idx = (g*4 + ks)*64 + lane;
// lane: row = lane&31, k0 = ks*64 + (lane>>5)*32; lo = k0..+15, hi = +16..31.
__global__ void conv_fp8(const float* __restrict__ x,
                         const float* __restrict__ z,
                         int4v* __restrict__ q,
                         float* __restrict__ out0) {
    const int uid = blockIdx.x * 256 + threadIdx.x;   // < 131072
    if (uid == 0) out0[0] = 0.0f;                     // loss accumulator
    const int tensor = uid >> 16;                     // 0 = x, 1 = z
    const int idx    = uid & 65535;
    const int g    = idx >> 8;
    const int r    = idx & 255;
    const int ks   = r >> 6;
    const int lane = r & 63;
    const int row  = g * 32 + (lane & 31);
    const int k0   = ks * 64 + (lane >> 5) * 32;
    const float4* p = (const float4*)((tensor ? z : x) + row * KDIM + k0);

    int4v lo, hi;
#pragma unroll
    for (int i = 0; i < 4; i++) {
        float4 f = p[i];
        int v = __builtin_amdgcn_cvt_pk_fp8_f32(f.x, f.y, 0, false);
        v = __builtin_amdgcn_cvt_pk_fp8_f32(f.z, f.w, v, true);
        lo[i] = v;
    }
#pragma unroll
    for (int i = 0; i < 4; i++) {
        float4 f = p[4 + i];
        int v = __builtin_amdgcn_cvt_pk_fp8_f32(f.x, f.y, 0, false);
        v = __builtin_amdgcn_cvt_pk_fp8_f32(f.z, f.w, v, true);
        hi[i] = v;
    }
    q[tensor * 131072 + idx]         = lo;
    q[tensor * 131072 + 65536 + idx] = hi;
}

__device__ __forceinline__ int8v mk8(int4v lo, int4v hi) {
    int8v r;
    r[0] = lo[0]; r[1] = lo[1]; r[2] = lo[2]; r[3] = lo[3];
    r[4] = hi[0]; r[5] = hi[1]; r[6] = hi[2]; r[7] = hi[3];
    return r;
}

#define MFMA_FP8(a, b, c) \
    __builtin_amdgcn_mfma_scale_f32_32x32x64_f8f6f4((a), (b), (c), 0, 0, 0, 0x7F7F7F7F, 0, 0x7F7F7F7F)

// Softmax over i for column j=lane&31; COMPACT store: lanes 0..31 write
// Sp[tile*32 + j] (fp16). loss_fused divides by 32.
__device__ __forceinline__ void tile_epilogue_sp(const float16& c, __half* __restrict__ Sp,
                                                 int a, int b, int lane) {
    float m8[8], m4[4];
#pragma unroll
    for (int r = 0; r < 8; r++) m8[r] = fmaxf(c[2 * r], c[2 * r + 1]);
#pragma unroll
    for (int r = 0; r < 4; r++) m4[r] = fmaxf(m8[2 * r], m8[2 * r + 1]);
    float m = fmaxf(fmaxf(m4[0], m4[1]), fmaxf(m4[2], m4[3]));
    m = fmaxf(m, __shfl_xor(m, 32, 64));

    float s0 = 0.f, s1 = 0.f, s2 = 0.f, s3 = 0.f;
    float w0 = 0.f, w1 = 0.f, w2 = 0.f, w3 = 0.f;
#pragma unroll
    for (int r = 0; r < 16; r += 4) {
        float e0 = __expf(c[r + 0] - m);
        float e1 = __expf(c[r + 1] - m);
        float e2 = __expf(c[r + 2] - m);
        float e3 = __expf(c[r + 3] - m);
        s0 += e0; s1 += e1; s2 += e2; s3 += e3;
        w0 = fmaf(e0, c[r + 0], w0);
        w1 = fmaf(e1, c[r + 1], w1);
        w2 = fmaf(e2, c[r + 2], w2);
        w3 = fmaf(e3, c[r + 3], w3);
    }
    float se  = (s0 + s1) + (s2 + s3);
    float swe = (w0 + w1) + (w2 + w3);
    se  += __shfl_xor(se, 32, 64);
    swe += __shfl_xor(swe, 32, 64);
    float cv = swe * __builtin_amdgcn_rcpf(se);
    if (lane < 32)
        Sp[(((a << 8) + b) << 5) + lane] = __float2half_rn(cv);
}

// grid = 2048 (64 a-blocks x 32 b-blocks), 256 threads — R11's exact config.
// Block: 4 a-groups (full K) in 32KB LDS; wave w covers b-groups bblk*8+w*2.
// Wave tile 4a x 2b (128 AGPR acc, 8 chains), 2 waves/SIMD.
__global__ __launch_bounds__(256, 2)
void sim_fp8(const int4v* __restrict__ q, __half* __restrict__ Sp) {
    __shared__ int4v sA[2048];   // 32 KB: chunk c = ai*8 + ks*2 + h, 64 units

    const int tid  = threadIdx.x;
    const int lane = tid & 63;
    const int w    = tid >> 6;

    const int ablk = blockIdx.x >> 5;
    const int bblk = blockIdx.x & 31;
    const int ag0  = ablk * 4;
    const int bg0  = bblk * 8 + w * 2;

    // stage A: 2048 units in 32 chunks of 64; chunk = ai*8 + ks*2 + h.
#pragma unroll
    for (int i = 0; i < 8; i++) {
        const int c  = i * 4 + w;             // wave-uniform, 0..31
        const int ai = c >> 3;
        const int ks = (c >> 1) & 3;
        const int h  = c & 1;
        const int4v* g = q + h * 65536 + ((ag0 + ai) * 4 + ks) * 64 + lane;
        int4v* l = &sA[c * 64];
        __builtin_amdgcn_global_load_lds((gptr_as1)g, (lptr_as3)l, 16, 0, 0);
    }
    __syncthreads();

    const int4v* zq = q + 131072;

    float16 acc[4][2];
#pragma unroll
    for (int ai = 0; ai < 4; ai++)
#pragma unroll
        for (int bi = 0; bi < 2; bi++)
#pragma unroll
            for (int r = 0; r < 16; r++) acc[ai][bi][r] = 0.0f;

#pragma unroll
    for (int ks = 0; ks < 4; ks++) {
        const int u0 = ((bg0 + 0) * 4 + ks) * 64 + lane;
        const int u1 = ((bg0 + 1) * 4 + ks) * 64 + lane;
        int8v Ba = mk8(zq[u0], zq[65536 + u0]);
        int8v Bb = mk8(zq[u1], zq[65536 + u1]);
#pragma unroll
        for (int ai = 0; ai < 4; ai++) {
            const int base = (ai * 8 + ks * 2) * 64 + lane;
            int8v Af = mk8(sA[base], sA[base + 64]);
            acc[ai][0] = MFMA_FP8(Af, Ba, acc[ai][0]);
            acc[ai][1] = MFMA_FP8(Af, Bb, acc[ai][1]);
        }
    }

#pragma unroll
    for (int ai = 0; ai < 4; ai++)
#pragma unroll
        for (int bi = 0; bi < 2; bi++)
            tile_epilogue_sp(acc[ai][bi], Sp, ag0 + ai, bg0 + bi, lane);
}

// Fused compact-Sp -> loss: 256 blocks (block n) x 256 threads (thread k).
// rowS[k] = mean_j Sp[(n,k)], colS[k] = mean_j Sp[(k,n)]; lse both dirs;
// diag = rowS[n]; one atomicAdd per block into out (zeroed by conv_fp8).
__global__ void loss_fused(const __half* __restrict__ Sp, float* __restrict__ out) {
    const int n    = blockIdx.x;
    const int k    = threadIdx.x;
    const int lane = k & 63;
    const int wv   = k >> 6;

    const __half2* rp = (const __half2*)(Sp + ((size_t)(n * 256 + k) << 5));
    const __half2* cp = (const __half2*)(Sp + ((size_t)(k * 256 + n) << 5));
    float rs = 0.f, cs = 0.f;
#pragma unroll
    for (int i = 0; i < 16; i++) {
        float2 f = __half22float2(rp[i]);
        rs += f.x + f.y;
    }
#pragma unroll
    for (int i = 0; i < 16; i++) {
        float2 f = __half22float2(cp[i]);
        cs += f.x + f.y;
    }
    rs *= (1.0f / 32.0f);
    cs *= (1.0f / 32.0f);

    __shared__ float shm[8];
    __shared__ float shs[8];
    __shared__ float sdiag;
    if (k == n) sdiag = rs;

    float mr = rs, mc = cs;
#pragma unroll
    for (int off = 1; off < 64; off <<= 1) {
        mr = fmaxf(mr, __shfl_xor(mr, off, 64));
        mc = fmaxf(mc, __shfl_xor(mc, off, 64));
    }
    if (lane == 0) { shm[wv] = mr; shm[4 + wv] = mc; }
    __syncthreads();
    mr = fmaxf(fmaxf(shm[0], shm[1]), fmaxf(shm[2], shm[3]));
    mc = fmaxf(fmaxf(shm[4], shm[5]), fmaxf(shm[6], shm[7]));

    float er = __expf(rs - mr), ec = __expf(cs - mc);
#pragma unroll
    for (int off = 1; off < 64; off <<= 1) {
        er += __shfl_xor(er, off, 64);
        ec += __shfl_xor(ec, off, 64);
    }
    if (lane == 0) { shs[wv] = er; shs[4 + wv] = ec; }
    __syncthreads();
    if (k == 0) {
        float sr = (shs[0] + shs[1]) + (shs[2] + shs[3]);
        float sc = (shs[4] + shs[5]) + (shs[6] + shs[7]);
        float lse_row = mr + __logf(sr);
        float lse_col = mc + __logf(sc);
        atomicAdd(out, (lse_row + lse_col - 2.0f * sdiag) * (1.0f / 256.0f));
    }
}

// ======================= bf16 fallback (R10-proven) =======================
__global__ void conv_kernel(const float* __restrict__ x,
                            const float* __restrict__ z,
                            short8* __restrict__ outbf,
                            float* __restrict__ out0) {
    const int uid = blockIdx.x * 256 + threadIdx.x;
    if (uid == 0) out0[0] = 0.0f;
    const int u = uid & 262143;
    const float* src = (uid < 262144) ? x : z;
    const int g  = u >> 10;
    const int r  = u & 1023;
    const int ks = r >> 6;
    const int h  = (r >> 5) & 1;
    const int l  = r & 31;
    outbf[uid] = cvt8(src + ((g * 32 + l) * KDIM + ks * 16 + h * 8));
}

__device__ __forceinline__ void tile_epilogue_bf(const float16& c, float* __restrict__ S,
                                                 int a, int b, int lane) {
    float m8[8], m4[4];
#pragma unroll
    for (int r = 0; r < 8; r++) m8[r] = fmaxf(c[2 * r], c[2 * r + 1]);
#pragma unroll
    for (int r = 0; r < 4; r++) m4[r] = fmaxf(m8[2 * r], m8[2 * r + 1]);
    float m = fmaxf(fmaxf(m4[0], m4[1]), fmaxf(m4[2], m4[3]));
    m = fmaxf(m, __shfl_xor(m, 32, 64));

    float s0 = 0.f, s1 = 0.f, s2 = 0.f, s3 = 0.f;
    float w0 = 0.f, w1 = 0.f, w2 = 0.f, w3 = 0.f;
#pragma unroll
    for (int r = 0; r < 16; r += 4) {
        float e0 = __expf(c[r + 0] - m);
        float e1 = __expf(c[r + 1] - m);
        float e2 = __expf(c[r + 2] - m);
        float e3 = __expf(c[r + 3] - m);
        s0 += e0; s1 += e1; s2 += e2; s3 += e3;
        w0 = fmaf(e0, c[r + 0], w0);
        w1 = fmaf(e1, c[r + 1], w1);
        w2 = fmaf(e2, c[r + 2], w2);
        w3 = fmaf(e3, c[r + 3], w3);
    }
    float se  = (s0 + s1) + (s2 + s3);
    float swe = (w0 + w1) + (w2 + w3);
    se  += __shfl_xor(se, 32, 64);
    swe += __shfl_xor(swe, 32, 64);
    float cv = swe * __builtin_amdgcn_rcpf(se);
#pragma unroll
    for (int off = 1; off < 32; off <<= 1) cv += __shfl_xor(cv, off, 64);
    if (lane == 0) S[a * NTOK + b] = cv * (1.0f / 32.0f);
}

#define MFMA_BF16 __builtin_amdgcn_mfma_f32_32x32x16_bf16

template <bool F32SRC>
__global__ __launch_bounds__(256, 2)
void sim_kernel(const short8* __restrict__ xbf, const short8* __restrict__ zbf,
                const float* __restrict__ xf, const float* __restrict__ zf,
                float* __restrict__ S) {
    __shared__ short8 sA[4096];

    const int tid  = threadIdx.x;
    const int lane = tid & 63;
    const int w    = tid >> 6;
    const int l31  = lane & 31;
    const int half = lane >> 5;

    const int ablk = blockIdx.x >> 5;
    const int bblk = blockIdx.x & 31;
    const int ag0  = ablk * 4;
    const int bg0  = bblk * 8 + w * 2;

    float16 acc[4][2];
#pragma unroll
    for (int ai = 0; ai < 4; ai++)
#pragma unroll
        for (int bi = 0; bi < 2; bi++)
#pragma unroll
            for (int r = 0; r < 16; r++) acc[ai][bi][r] = 0.0f;

    if (!F32SRC) {
        const short8* asrc = xbf + (size_t)ablk * 4096;
#pragma unroll
        for (int i = 0; i < 16; i++) {
            const short8* g = asrc + i * 256 + w * 64 + lane;
            short8* l = &sA[i * 256 + w * 64];
            __builtin_amdgcn_global_load_lds((gptr_as1)g, (lptr_as3)l, 16, 0, 0);
        }
        __syncthreads();

        const short8* pb0 = zbf + (bg0 + 0) * 1024 + lane;
        const short8* pb1 = zbf + (bg0 + 1) * 1024 + lane;
        short8 Ba = pb0[0];
        short8 Bb = pb1[0];
#pragma unroll
        for (int ks = 0; ks < 16; ks++) {
            short8 Na, Nb;
            if (ks < 15) { Na = pb0[(ks + 1) * 64]; Nb = pb1[(ks + 1) * 64]; }
            short8 A0 = sA[ks * 64 + lane];
            short8 A1 = sA[1024 + ks * 64 + lane];
            short8 A2 = sA[2048 + ks * 64 + lane];
            short8 A3 = sA[3072 + ks * 64 + lane];
            acc[0][0] = MFMA_BF16(A0, Ba, acc[0][0], 0, 0, 0);
            acc[0][1] = MFMA_BF16(A0, Bb, acc[0][1], 0, 0, 0);
            acc[1][0] = MFMA_BF16(A1, Ba, acc[1][0], 0, 0, 0);
            acc[1][1] = MFMA_BF16(A1, Bb, acc[1][1], 0, 0, 0);
            acc[2][0] = MFMA_BF16(A2, Ba, acc[2][0], 0, 0, 0);
            acc[2][1] = MFMA_BF16(A2, Bb, acc[2][1], 0, 0, 0);
            acc[3][0] = MFMA_BF16(A3, Ba, acc[3][0], 0, 0, 0);
            acc[3][1] = MFMA_BF16(A3, Bb, acc[3][1], 0, 0, 0);
            Ba = Na; Bb = Nb;
        }
    } else {
        const float* fb0 = zf + (((bg0 + 0) * 32 + l31) * KDIM + half * 8);
        const float* fb1 = zf + (((bg0 + 1) * 32 + l31) * KDIM + half * 8);
#pragma unroll 1
        for (int ks = 0; ks < 16; ks++) {
            short8 Ba = cvt8(fb0 + ks * 16);
            short8 Bb = cvt8(fb1 + ks * 16);
#pragma unroll
            for (int ai = 0; ai < 4; ai++) {
                const float* fa = xf + (((ag0 + ai) * 32 + l31) * KDIM + half * 8);
                short8 Af = cvt8(fa + ks * 16);
                acc[ai][0] = MFMA_BF16(Af, Ba, acc[ai][0], 0, 0, 0);
                acc[ai][1] = MFMA_BF16(Af, Bb, acc[ai][1], 0, 0, 0);
            }
        }
    }

#pragma unroll
    for (int ai = 0; ai < 4; ai++)
#pragma unroll
        for (int bi = 0; bi < 2; bi++)
            tile_epilogue_bf(acc[ai][bi], S, ag0 + ai, bg0 + bi, lane);
}

__global__ void loss_part(const float* __restrict__ S, float* __restrict__ out) {
    const int lane = threadIdx.x & 63;
    const int wid  = threadIdx.x >> 6;
    const int n    = blockIdx.x * 4 + wid;

    float cv[4], rv[4];
#pragma unroll
    for (int k = 0; k < 4; k++) {
        const int t = lane + 64 * k;
        cv[k] = S[t * NTOK + n];
        rv[k] = S[n * NTOK + t];
    }
    float m = fmaxf(fmaxf(cv[0], cv[1]), fmaxf(cv[2], cv[3]));
#pragma unroll
    for (int off = 1; off < 64; off <<= 1) m = fmaxf(m, __shfl_xor(m, off, 64));
    float s = 0.0f;
#pragma unroll
    for (int k = 0; k < 4; k++) s += __expf(cv[k] - m);
#pragma unroll
    for (int off = 1; off < 64; off <<= 1) s += __shfl_xor(s, off, 64);
    float lse_col = m + __logf(s);

    float m2 = fmaxf(fmaxf(rv[0], rv[1]), fmaxf(rv[2], rv[3]));
#pragma unroll
    for (int off = 1; off < 64; off <<= 1) m2 = fmaxf(m2, __shfl_xor(m2, off, 64));
    float s2 = 0.0f;
#pragma unroll
    for (int k = 0; k < 4; k++) s2 += __expf(rv[k] - m2);
#pragma unroll
    for (int off = 1; off < 64; off <<= 1) s2 += __shfl_xor(s2, off, 64);
    float lse_row = m2 + __logf(s2);

    __shared__ float red[4];
    if (lane == 0) {
        float diag = S[n * NTOK + n];
        red[wid] = (lse_col - diag) + (lse_row - diag);
    }
    __syncthreads();
    if (threadIdx.x == 0)
        atomicAdd(out, (red[0] + red[1] + red[2] + red[3]) * (1.0f / 256.0f));
}

__global__ void zero_kernel(float* __restrict__ out) {
    out[0] = 0.0f;
}

extern "C" void kernel_launch(void* const* d_in, const int* in_sizes, int n_in,
                              void* d_out, int out_size, void* d_ws, size_t ws_size,
                              hipStream_t stream) {
    const float* x = (const float*)d_in[0];   // [256,32,256]
    const float* z = (const float*)d_in[1];   // [256,32,256]
    float* out = (float*)d_out;

    const size_t q_bytes  = 262144ull * 16ull;           // 4 MB fp8 (lo/hi planes)
    const size_t sp_bytes = 65536ull * 32ull * 2ull;     // 4 MB compact fp16 Sp
    const size_t s_bytes  = 256ull * 256ull * 4ull;      // 256 KB
    const size_t bf_bytes = 524288ull * 16ull;           // 8 MB bf16 (fallback)

    if (ws_size >= q_bytes + sp_bytes) {
        int4v*  q  = (int4v*)d_ws;
        __half* Sp = (__half*)((char*)d_ws + q_bytes);
        conv_fp8<<<512, 256, 0, stream>>>(x, z, q, out);
        sim_fp8<<<2048, 256, 0, stream>>>(q, Sp);
        loss_fused<<<256, 256, 0, stream>>>(Sp, out);
    } else if (ws_size >= bf_bytes + s_bytes) {
        short8* xbf = (short8*)d_ws;
        short8* zbf = xbf + 262144;
        float*  S   = (float*)((char*)d_ws + bf_bytes);
        conv_kernel<<<2048, 256, 0, stream>>>(x, z, (short8*)d_ws, out);
        sim_kernel<false><<<2048, 256, 0, stream>>>(xbf, zbf, nullptr, nullptr, S);
        loss_part<<<64, 256, 0, stream>>>(S, out);
    } else {
        float* S = (float*)d_ws;
        zero_kernel<<<1, 1, 0, stream>>>(out);
        sim_kernel<true><<<2048, 256, 0, stream>>>(nullptr, nullptr, x, z, S);
        loss_part<<<64, 256, 0, stream>>>(S, out);
    }
}